// Round 1
// baseline (419.102 us; speedup 1.0000x reference)
//
#include <hip/hip_runtime.h>
#include <hip/hip_bf16.h>

// Problem: B=16, N=1024, D=768, H=12, E=64.  M = B*N = 16384.
// qk = x@Wqk^T+b -> split (h,e,2) -> Q,K [b,h,n,e]; v = x@Wv^T+b -> V [b,h,n,e]
// attn = softmax(QK^T)/sqrt(768); out = (attn@V) concat -> @Wo^T + b  (f32 out)
//
// Pipeline: cvt_x -> pack_w -> gemm_bt<0> (QKV, writes Q,K,V^T bf16) ->
//           attn (flash, writes concat bf16) -> gemm_bt<1> (f32 out)
// Workspace usage: ~105.4 MB (concat aliases x_bf16).

typedef __attribute__((ext_vector_type(4))) float  f32x4;
typedef __attribute__((ext_vector_type(8))) short  s16x8;
typedef __attribute__((ext_vector_type(4))) short  s16x4;

static __device__ __forceinline__ short f2bf(float f) {
  unsigned u = __builtin_bit_cast(unsigned, f);
  u += 0x7fff + ((u >> 16) & 1);          // round-to-nearest-even
  return (short)(u >> 16);
}

static __device__ __forceinline__ void gload16(const void* g, void* l) {
  __builtin_amdgcn_global_load_lds(
      (const __attribute__((address_space(1))) void*)g,
      (__attribute__((address_space(3))) void*)l, 16, 0, 0);
}

// ---------------------------------------------------------------- converts --
__global__ void cvt_x_kernel(const float* __restrict__ x, short* __restrict__ xb, int n4) {
  int stride = gridDim.x * blockDim.x;
  for (int t = blockIdx.x * blockDim.x + threadIdx.x; t < n4; t += stride) {
    f32x4 v = *(const f32x4*)(x + 4 * (size_t)t);
    s16x4 o;
#pragma unroll
    for (int i = 0; i < 4; ++i) o[i] = f2bf(v[i]);
    *(s16x4*)(xb + 4 * (size_t)t) = o;
  }
}

// Pack weights bf16 into Wall[3072][768]:
//  rows [0,768)    = Q  : Wqk row h*128 + e*2 + 0   (j = h*64+e)
//  rows [768,1536) = K  : Wqk row h*128 + e*2 + 1
//  rows [1536,2304)= V  : Wv  row j-1536
//  rows [2304,3072)= Wo : Wo  row j-2304
__global__ void pack_w_kernel(const float* __restrict__ Wqk, const float* __restrict__ qkb,
                              const float* __restrict__ Wv,  const float* __restrict__ vb,
                              const float* __restrict__ Wo,  const float* __restrict__ ob,
                              short* __restrict__ Wall, float* __restrict__ ball) {
  int stride = gridDim.x * blockDim.x;
  for (int t = blockIdx.x * blockDim.x + threadIdx.x; t < 3072 * 768; t += stride) {
    int j = t / 768, k = t - j * 768;
    float v;
    if (j < 768)        v = Wqk[(((j   >> 6) << 7) + ((j    & 63) << 1) + 0) * 768 + k];
    else if (j < 1536)  { int jj = j -  768; v = Wqk[(((jj >> 6) << 7) + ((jj & 63) << 1) + 1) * 768 + k]; }
    else if (j < 2304)  { int jj = j - 1536; v = Wv[jj * 768 + k]; }
    else                { int jj = j - 2304; v = Wo[jj * 768 + k]; }
    Wall[t] = f2bf(v);
  }
  for (int t = blockIdx.x * blockDim.x + threadIdx.x; t < 3072; t += stride) {
    float v;
    if (t < 768)        v = qkb[((t >> 6) << 7) + ((t & 63) << 1)];
    else if (t < 1536)  { int jj = t -  768; v = qkb[((jj >> 6) << 7) + ((jj & 63) << 1) + 1]; }
    else if (t < 2304)  v = vb[t - 1536];
    else                v = ob[t - 2304];
    ball[t] = v;
  }
}

// ------------------------------------------------------------------- GEMM ---
// C[m][j] = sum_k A[m][k]*Bw[j][k] + bias[j].  A: Mx768 bf16, Bw: Nx768 bf16.
// 128x128 tile, BK=32, 4 waves (2x2), 16x16x32 MFMA, global_load_lds staging.
// MODE 0: N=2304, scatter epilogue -> Qo/Ko (b,h,n,e) and Vo transposed (b,h,e,n)
// MODE 1: N=768,  Fo[m*768+j] = acc + bias  (f32)
template <int MODE>
__global__ __launch_bounds__(256)
void gemm_bt(const short* __restrict__ A, const short* __restrict__ Bw,
             const float* __restrict__ bias,
             short* __restrict__ Qo, short* __restrict__ Ko, short* __restrict__ Vo,
             float* __restrict__ Fo) {
  __shared__ short As[2][128 * 32];
  __shared__ short Bs[2][128 * 32];
  const int tid = threadIdx.x;
  const int lane = tid & 63, wid = tid >> 6;
  const int wr = wid >> 1, wc = wid & 1;
  const int lrow = lane & 15, lk = lane >> 4;
  const int m0 = blockIdx.y * 128;
  const int n0 = blockIdx.x * 128;
  const int r2 = tid >> 2, c2 = (tid & 3) * 8;   // staging: 2 passes of 64 rows

  f32x4 acc[4][4] = {};

  {
    const short* ga = A  + (size_t)(m0 + r2) * 768 + c2;
    const short* gb = Bw + (size_t)(n0 + r2) * 768 + c2;
    gload16(ga,            &As[0][tid * 8]);
    gload16(ga + 64 * 768, &As[0][(256 + tid) * 8]);
    gload16(gb,            &Bs[0][tid * 8]);
    gload16(gb + 64 * 768, &Bs[0][(256 + tid) * 8]);
  }

  for (int kt = 0; kt < 24; ++kt) {
    __syncthreads();                       // drains vmcnt: buf[kt&1] ready
    const int cur = kt & 1;
    if (kt + 1 < 24) {
      const int nxt = cur ^ 1;
      const short* ga = A  + (size_t)(m0 + r2) * 768 + (kt + 1) * 32 + c2;
      const short* gb = Bw + (size_t)(n0 + r2) * 768 + (kt + 1) * 32 + c2;
      gload16(ga,            &As[nxt][tid * 8]);
      gload16(ga + 64 * 768, &As[nxt][(256 + tid) * 8]);
      gload16(gb,            &Bs[nxt][tid * 8]);
      gload16(gb + 64 * 768, &Bs[nxt][(256 + tid) * 8]);
    }
    s16x8 a[4], b[4];
#pragma unroll
    for (int mf = 0; mf < 4; ++mf)
      a[mf] = *(const s16x8*)&As[cur][(wr * 64 + mf * 16 + lrow) * 32 + lk * 8];
#pragma unroll
    for (int nf = 0; nf < 4; ++nf)
      b[nf] = *(const s16x8*)&Bs[cur][(wc * 64 + nf * 16 + lrow) * 32 + lk * 8];
#pragma unroll
    for (int mf = 0; mf < 4; ++mf)
#pragma unroll
      for (int nf = 0; nf < 4; ++nf)
        acc[mf][nf] = __builtin_amdgcn_mfma_f32_16x16x32_bf16(a[mf], b[nf], acc[mf][nf], 0, 0, 0);
  }

  // epilogue: C/D layout col = lane&15, row = (lane>>4)*4 + i  [verified m89/m91]
  const int g4 = lk * 4;
#pragma unroll
  for (int nf = 0; nf < 4; ++nf) {
    const int jc = n0 + wc * 64 + nf * 16 + lrow;
    const float bs = bias[jc];
#pragma unroll
    for (int mf = 0; mf < 4; ++mf) {
      f32x4 v = acc[mf][nf];
      const int mb = m0 + wr * 64 + mf * 16 + g4;
      if (MODE == 1) {
#pragma unroll
        for (int i = 0; i < 4; ++i)
          Fo[(size_t)(mb + i) * 768 + jc] = v[i] + bs;
      } else {
        const int bi = mb >> 10, n = mb & 1023;
        if (jc < 768) {                       // Q [b,h,n,e]
          const int h = jc >> 6, e = jc & 63;
          short* dst = Qo + (((size_t)bi * 12 + h) << 16) + (n << 6) + e;
#pragma unroll
          for (int i = 0; i < 4; ++i) dst[i << 6] = f2bf(v[i] + bs);
        } else if (jc < 1536) {               // K [b,h,n,e]
          const int jj = jc - 768;
          const int h = jj >> 6, e = jj & 63;
          short* dst = Ko + (((size_t)bi * 12 + h) << 16) + (n << 6) + e;
#pragma unroll
          for (int i = 0; i < 4; ++i) dst[i << 6] = f2bf(v[i] + bs);
        } else {                              // V^T [b,h,e,n]: 4 consecutive n -> 8B store
          const int jj = jc - 1536;
          const int h = jj >> 6, e = jj & 63;
          s16x4 pk;
#pragma unroll
          for (int i = 0; i < 4; ++i) pk[i] = f2bf(v[i] + bs);
          *(s16x4*)(Vo + (((size_t)bi * 12 + h) * 64 + e) * 1024 + n) = pk;
        }
      }
    }
  }
}

// -------------------------------------------------------------- attention ---
// grid (8 qtiles, 192 bh). 4 waves x 32 q-rows. KV tile = 128.
// Q in regs; K [128][64+8pad], V^T [64][128+8pad] in LDS (reg-staged, padded);
// P transposed via per-wave padded LDS in two 64-col halves.
__global__ __launch_bounds__(256)
void attn_kernel(const short* __restrict__ Q, const short* __restrict__ K,
                 const short* __restrict__ VT, short* __restrict__ Co) {
  __shared__ short Ks[128 * 72];
  __shared__ short Vs[64 * 136];
  __shared__ short Ps[4][32 * 72];
  const int tid = threadIdx.x, lane = tid & 63, wid = tid >> 6;
  const int lrow = lane & 15, lk = lane >> 4;
  const int qt = blockIdx.x, bh = blockIdx.y;
  const int bi = bh / 12, h = bh - bi * 12;
  const int q0 = qt * 128 + wid * 32;
  const size_t base = (size_t)bh << 16;

  s16x8 qf[2][2];
#pragma unroll
  for (int mf = 0; mf < 2; ++mf)
#pragma unroll
    for (int kk = 0; kk < 2; ++kk)
      qf[mf][kk] = *(const s16x8*)&Q[base + (q0 + mf * 16 + lrow) * 64 + kk * 32 + lk * 8];

  f32x4 o[2][4] = {};
  float mr[2][4], lr[2][4];
#pragma unroll
  for (int mf = 0; mf < 2; ++mf)
#pragma unroll
    for (int i = 0; i < 4; ++i) { mr[mf][i] = -1e30f; lr[mf][i] = 0.f; }

  const int krow = tid >> 3, kcb = (tid & 7) * 8;    // K: 32 rows/pass
  const int vrow = tid >> 4, vcb = (tid & 15) * 8;   // V^T: 16 rows/pass

  for (int kv0 = 0; kv0 < 1024; kv0 += 128) {
    __syncthreads();                                  // prev tile reads done
#pragma unroll
    for (int p = 0; p < 4; ++p) {
      s16x8 kv = *(const s16x8*)&K[base + (size_t)(kv0 + p * 32 + krow) * 64 + kcb];
      *(s16x8*)&Ks[(p * 32 + krow) * 72 + kcb] = kv;
      s16x8 vv = *(const s16x8*)&VT[base + (size_t)(p * 16 + vrow) * 1024 + kv0 + vcb];
      *(s16x8*)&Vs[(p * 16 + vrow) * 136 + vcb] = vv;
    }
    __syncthreads();                                  // tile visible

    // S = Q K^T  (rows q, cols kv)
    f32x4 s[2][8];
#pragma unroll
    for (int mf = 0; mf < 2; ++mf)
#pragma unroll
      for (int nf = 0; nf < 8; ++nf) s[mf][nf] = f32x4{0.f, 0.f, 0.f, 0.f};
#pragma unroll
    for (int nf = 0; nf < 8; ++nf) {
      s16x8 b0 = *(const s16x8*)&Ks[(nf * 16 + lrow) * 72 + lk * 8];
      s16x8 b1 = *(const s16x8*)&Ks[(nf * 16 + lrow) * 72 + 32 + lk * 8];
#pragma unroll
      for (int mf = 0; mf < 2; ++mf) {
        s[mf][nf] = __builtin_amdgcn_mfma_f32_16x16x32_bf16(qf[mf][0], b0, s[mf][nf], 0, 0, 0);
        s[mf][nf] = __builtin_amdgcn_mfma_f32_16x16x32_bf16(qf[mf][1], b1, s[mf][nf], 0, 0, 0);
      }
    }

    // online softmax (raw scores; scale applied at the very end)
#pragma unroll
    for (int mf = 0; mf < 2; ++mf) {
#pragma unroll
      for (int i = 0; i < 4; ++i) {
        float pm = s[mf][0][i];
#pragma unroll
        for (int nf = 1; nf < 8; ++nf) pm = fmaxf(pm, s[mf][nf][i]);
#pragma unroll
        for (int d = 1; d < 16; d <<= 1) pm = fmaxf(pm, __shfl_xor(pm, d, 64));
        const float mo = mr[mf][i];
        const float mn = fmaxf(mo, pm);
        const float sc = __expf(mo - mn);
        float rs = 0.f;
#pragma unroll
        for (int nf = 0; nf < 8; ++nf) {
          float p = __expf(s[mf][nf][i] - mn);
          s[mf][nf][i] = p;
          rs += p;
        }
#pragma unroll
        for (int d = 1; d < 16; d <<= 1) rs += __shfl_xor(rs, d, 64);
        lr[mf][i] = lr[mf][i] * sc + rs;
        mr[mf][i] = mn;
#pragma unroll
        for (int ef = 0; ef < 4; ++ef) o[mf][ef][i] *= sc;
      }
    }

    // P -> per-wave LDS (transpose), PV MFMA; two 64-col halves to save LDS
    short* pw = Ps[wid];
#pragma unroll
    for (int half = 0; half < 2; ++half) {
#pragma unroll
      for (int mf = 0; mf < 2; ++mf)
#pragma unroll
        for (int nh = 0; nh < 4; ++nh) {
          const int nf = half * 4 + nh;
#pragma unroll
          for (int i = 0; i < 4; ++i)
            pw[(mf * 16 + lk * 4 + i) * 72 + nh * 16 + lrow] = f2bf(s[mf][nf][i]);
        }
#pragma unroll
      for (int kh = 0; kh < 2; ++kh) {
        const int kvf = half * 2 + kh;
        s16x8 pa[2];
#pragma unroll
        for (int mf = 0; mf < 2; ++mf)
          pa[mf] = *(const s16x8*)&pw[(mf * 16 + lrow) * 72 + kh * 32 + lk * 8];
#pragma unroll
        for (int ef = 0; ef < 4; ++ef) {
          s16x8 vb = *(const s16x8*)&Vs[(ef * 16 + lrow) * 136 + kvf * 32 + lk * 8];
#pragma unroll
          for (int mf = 0; mf < 2; ++mf)
            o[mf][ef] = __builtin_amdgcn_mfma_f32_16x16x32_bf16(pa[mf], vb, o[mf][ef], 0, 0, 0);
        }
      }
    }
  }

  // epilogue: concat[b,n, h*64+e] = O / (l * sqrt(768))
  const float isq = 0.03608439182435161f;   // 1/sqrt(768)
#pragma unroll
  for (int mf = 0; mf < 2; ++mf) {
#pragma unroll
    for (int i = 0; i < 4; ++i) {
      const float inv = isq / lr[mf][i];
      const int q = q0 + mf * 16 + lk * 4 + i;
      short* dst = Co + ((size_t)(bi * 1024 + q)) * 768 + h * 64;
#pragma unroll
      for (int ef = 0; ef < 4; ++ef)
        dst[ef * 16 + lrow] = f2bf(o[mf][ef][i] * inv);
    }
  }
}

// ------------------------------------------------------------------ launch --
extern "C" void kernel_launch(void* const* d_in, const int* in_sizes, int n_in,
                              void* d_out, int out_size, void* d_ws, size_t ws_size,
                              hipStream_t stream) {
  const float* x     = (const float*)d_in[0];
  const float* Wqk_w = (const float*)d_in[1];
  const float* Wqk_b = (const float*)d_in[2];
  const float* Wv_w  = (const float*)d_in[3];
  const float* Wv_b  = (const float*)d_in[4];
  const float* Wo_w  = (const float*)d_in[5];
  const float* Wo_b  = (const float*)d_in[6];
  float* out = (float*)d_out;

  char* w = (char*)d_ws;
  short* xb   = (short*)(w);                 // 25,165,824 B  (reused as concat)
  short* Wall = (short*)(w + 25165824);      //  4,718,592 B
  float* ball = (float*)(w + 29884416);      //     12,288 B
  short* Qb   = (short*)(w + 29896704);      // 25,165,824 B
  short* Kb   = (short*)(w + 55062528);      // 25,165,824 B
  short* VTb  = (short*)(w + 80228352);      // 25,165,824 B -> total 105,394,176 B
  short* Co   = xb;                          // alias: x_bf16 dead after gemm<0>

  cvt_x_kernel<<<2048, 256, 0, stream>>>(x, xb, 16384 * 768 / 4);
  pack_w_kernel<<<1024, 256, 0, stream>>>(Wqk_w, Wqk_b, Wv_w, Wv_b, Wo_w, Wo_b, Wall, ball);
  gemm_bt<0><<<dim3(18, 128), 256, 0, stream>>>(xb, Wall, ball, Qb, Kb, VTb, nullptr);
  attn_kernel<<<dim3(8, 192), 256, 0, stream>>>(Qb, Kb, VTb, Co);
  gemm_bt<1><<<dim3(6, 128), 256, 0, stream>>>(Co, Wall + 2304 * 768, ball + 2304,
                                               nullptr, nullptr, nullptr, out);
}